// Round 7
// baseline (289.892 us; speedup 1.0000x reference)
//
#include <hip/hip_runtime.h>
#include <hip/hip_bf16.h>

typedef __attribute__((ext_vector_type(8))) short short8;
typedef __attribute__((ext_vector_type(4))) short short4v;
typedef __attribute__((ext_vector_type(4))) float f32x4;

#define MFMA16(a, b, c) __builtin_amdgcn_mfma_f32_16x16x32_bf16(a, b, c, 0, 0, 0)

__device__ __forceinline__ unsigned short f2bf(float f) {
    unsigned int u = __float_as_uint(f);
    unsigned int r = u + 0x7fffu + ((u >> 16) & 1u);
    return (unsigned short)(r >> 16);
}
__device__ __forceinline__ float bf2f(unsigned short h) {
    return __uint_as_float(((unsigned int)h) << 16);
}
__device__ __forceinline__ unsigned int pk2(float lo, float hi) {
    return (unsigned int)f2bf(lo) | ((unsigned int)f2bf(hi) << 16);
}

__device__ __forceinline__ void async16(const void* g, void* l) {
    __builtin_amdgcn_global_load_lds(
        (const __attribute__((address_space(1))) unsigned int*)g,
        (__attribute__((address_space(3))) unsigned int*)l, 16, 0, 0);
}

#define S_BARRIER() asm volatile("s_barrier" ::: "memory")
#define SCHED_FENCE() __builtin_amdgcn_sched_barrier(0)

// ---------------- fp32 -> bf16 conversion for the 4 weight matrices (one launch) ------
__global__ __launch_bounds__(256) void cvt4_kernel(const float* __restrict__ w0,
                                                   const float* __restrict__ w1,
                                                   const float* __restrict__ w2,
                                                   const float* __restrict__ w3,
                                                   unsigned short* __restrict__ o0,
                                                   unsigned short* __restrict__ o1,
                                                   unsigned short* __restrict__ o2,
                                                   unsigned short* __restrict__ o3,
                                                   int n4) {
    int wsel = blockIdx.x >> 7;
    int lb = blockIdx.x & 127;
    const float* in = wsel == 0 ? w0 : wsel == 1 ? w1 : wsel == 2 ? w2 : w3;
    unsigned short* out = wsel == 0 ? o0 : wsel == 1 ? o1 : wsel == 2 ? o2 : o3;
    for (int i = lb * 256 + threadIdx.x; i < n4; i += 32768) {
        float4 v = reinterpret_cast<const float4*>(in)[i];
        short4v p;
        p[0] = (short)f2bf(v.x); p[1] = (short)f2bf(v.y);
        p[2] = (short)f2bf(v.z); p[3] = (short)f2bf(v.w);
        reinterpret_cast<short4v*>(out)[i] = p;
    }
}

// ---------------- 8-phase GEMM: C[M,1024] = A[M,1024] @ B[1024,1024]^T + bias ----------
// R6 structure (BM=BN=256, BK=64, 2 K-tiles/iter, 8 waves 2Mx4N, 2x64KB LDS, 3-bit XOR
// swizzle -> 0 bank conflicts, counted vmcnt). New in R7: AFP32=1 reads A as fp32 and
// fuses the bf16 conversion into staging (T14 issue-early/pack-late reg-staging; issue
// placed BEFORE pack so compiler-inserted waits stay counted, never drain). B staging
// stays async16 from pre-converted bf16 weights. AFP32=0 = R6 path (async16 A).
// MODE 0: elu+1, bf16 out, normal layout        (Q projection)
// MODE 1: elu+1, bf16 out, transposed           (K projection -> Kt)
// MODE 2: plain, bf16 out, transposed           (V projection -> vT)
// MODE 3: plain, fp32 out, normal layout        (output projection)
template <int MODE, int AFP32>
__global__ __launch_bounds__(512, 2) void gemm8p(const void* __restrict__ Araw,
                                                 const unsigned short* __restrict__ B,
                                                 const float* __restrict__ bias,
                                                 void* __restrict__ out) {
    __shared__ __align__(16) char lds[131072];  // 2 bufs x (Aq0 16K, Aq1 16K, B0 16K, B1 16K)

    const int tid = threadIdx.x;             // 0..511
    const int lane = tid & 63, wid = tid >> 6;
    const int wr = wid >> 2, wc = wid & 3;   // wave out: rows wr*128, cols wc*64
    const int lr = lane & 15, lg = lane >> 4;

    // XCD-aware bijective swizzle (gridDim.x == 256)
    const int nwg = gridDim.x;
    const int bid = blockIdx.x;
    const int swz = (bid & 7) * (nwg >> 3) + (bid >> 3);
    const int bm = swz >> 2, bn = swz & 3;
    const long row0 = (long)bm * 256;
    const long col0 = (long)bn * 256;

    // ---- staging sources (pre-swizzled; LDS dest linear) ----
    // half = [128 phys rows][64 k]; chunk s = g*512+tid: pr=s>>3, dc=(s&7)^(pr&7)
    const int ESZ = AFP32 ? 4 : 2;
    const char* srcAbase[2];
    const unsigned short* srcB[2];
    int dstOff[2];
#pragma unroll
    for (int g = 0; g < 2; ++g) {
        int s = g * 512 + tid;
        int pr = s >> 3;
        int dc = (s & 7) ^ (pr & 7);
        // A quadrant q phys row pr -> global row (pr&63) + 64*q + 128*(pr>>6)
        srcAbase[g] = (const char*)Araw +
                      (long)((row0 + (pr & 63) + 128 * (pr >> 6)) * 1024 + dc * 8) * ESZ;
        // B half h phys row pr -> global row col0 + h*128 + pr
        srcB[g] = B + (col0 + pr) * 1024 + dc * 8;
        dstOff[g] = s * 16;
    }

#define STG_AQ(BB, Q, KT) do {                                                  \
        async16(srcAbase[0] + ((Q) * 65536 + (KT) * 64) * 2,                    \
                lds + (BB) * 65536 + (Q) * 16384 + dstOff[0]);                  \
        async16(srcAbase[1] + ((Q) * 65536 + (KT) * 64) * 2,                    \
                lds + (BB) * 65536 + (Q) * 16384 + dstOff[1]); } while (0)
#define STG_BH(BB, H, KT) do {                                                  \
        async16(srcB[0] + (H) * 131072 + (KT) * 64,                             \
                lds + (BB) * 65536 + 32768 + (H) * 16384 + dstOff[0]);          \
        async16(srcB[1] + (H) * 131072 + (KT) * 64,                             \
                lds + (BB) * 65536 + 32768 + (H) * 16384 + dstOff[1]); } while (0)
#define A_ISSUE(ARR, Q, KT) do {                                                \
        const char* s0_ = srcAbase[0] + ((Q) * 65536 + (KT) * 64) * 4;          \
        const char* s1_ = srcAbase[1] + ((Q) * 65536 + (KT) * 64) * 4;          \
        ARR[0] = *(const float4*)s0_;  ARR[1] = *(const float4*)(s0_ + 16);     \
        ARR[2] = *(const float4*)s1_;  ARR[3] = *(const float4*)(s1_ + 16); } while (0)
#define A_PACK(ARR, BB, Q) do {                                                 \
        uint4 w0_, w1_;                                                         \
        w0_.x = pk2(ARR[0].x, ARR[0].y); w0_.y = pk2(ARR[0].z, ARR[0].w);       \
        w0_.z = pk2(ARR[1].x, ARR[1].y); w0_.w = pk2(ARR[1].z, ARR[1].w);       \
        w1_.x = pk2(ARR[2].x, ARR[2].y); w1_.y = pk2(ARR[2].z, ARR[2].w);       \
        w1_.z = pk2(ARR[3].x, ARR[3].y); w1_.w = pk2(ARR[3].z, ARR[3].w);       \
        *(uint4*)(lds + (BB) * 65536 + (Q) * 16384 + dstOff[0]) = w0_;          \
        *(uint4*)(lds + (BB) * 65536 + (Q) * 16384 + dstOff[1]) = w1_; } while (0)

    // ---- ds_read byte offsets ----
    const int ch0 = (((0 * 4 + lg) ^ (lr & 7)) << 4);
    const int ch1 = (((1 * 4 + lg) ^ (lr & 7)) << 4);
    const int aB0 = (64 * wr + lr) * 128 + ch0;           // + q*16384 + (m&3)*2048
    const int aB1 = (64 * wr + lr) * 128 + ch1;
    const int bB0 = 32768 + (wc >> 1) * 16384 + ((wc & 1) * 64 + lr) * 128 + ch0;
    const int bB1 = 32768 + (wc >> 1) * 16384 + ((wc & 1) * 64 + lr) * 128 + ch1;

    f32x4 acc[8][4] = {};
    short8 b0[4], b1[4];
    float4 apreA[4], apreB[4];

#define GATEN() do { if (AFP32) asm volatile("s_waitcnt vmcnt(6)" ::: "memory");     \
                     else       asm volatile("s_waitcnt vmcnt(4)" ::: "memory");     \
                     SCHED_FENCE(); } while (0)
#define GATE0() do { asm volatile("s_waitcnt vmcnt(0)" ::: "memory"); SCHED_FENCE(); } while (0)
#define MFMA_BLOCK(MB, BV) do {                                                 \
        S_BARRIER();                                                            \
        asm volatile("s_waitcnt lgkmcnt(0)" ::: "memory");                      \
        SCHED_FENCE();                                                          \
        __builtin_amdgcn_s_setprio(1);                                          \
        _Pragma("unroll") for (int m = 0; m < 4; ++m)                           \
            _Pragma("unroll") for (int n = 0; n < 4; ++n)                       \
                acc[(MB) + m][n] = MFMA16(a[m], BV[n], acc[(MB) + m][n]);       \
        __builtin_amdgcn_s_setprio(0);                                          \
        SCHED_FENCE();                                                          \
        S_BARRIER(); } while (0)
#define LOAD_A(BUFB, ABASE, Q) do {                                             \
        _Pragma("unroll") for (int m = 0; m < 4; ++m)                           \
            a[m] = *(const short8*)(lds + (BUFB) + (Q) * 16384 + (ABASE) + m * 2048); } while (0)
#define LOAD_B(BUFB, BBASE, BV) do {                                            \
        _Pragma("unroll") for (int n = 0; n < 4; ++n)                           \
            BV[n] = *(const short8*)(lds + (BUFB) + (BBASE) + n * 2048); } while (0)

    // ---- prologue ----
    if (AFP32) {
        STG_BH(0, 0, 0); STG_BH(0, 1, 0); STG_BH(1, 0, 1);
        float4 t0[4], t1[4], t2[4];
        A_ISSUE(t0, 0, 0); A_ISSUE(t1, 1, 0);
        A_PACK(t0, 0, 0);
        A_ISSUE(t2, 0, 1);
        A_PACK(t1, 0, 1);
        A_PACK(t2, 1, 0);
        A_ISSUE(apreA, 1, 1);
        asm volatile("s_waitcnt lgkmcnt(0)" ::: "memory");
        SCHED_FENCE();
        S_BARRIER();
    } else {
        STG_AQ(0, 0, 0); STG_BH(0, 0, 0); STG_BH(0, 1, 0); STG_AQ(0, 1, 0);
        STG_AQ(1, 0, 1); STG_BH(1, 0, 1);
        GATEN();
        S_BARRIER();
    }

#pragma unroll 1
    for (int t = 0; t < 7; ++t) {
        const int ktA = 2 * t + 1, ktB = 2 * t + 2, ktC = 2 * t + 3;
        { // P1: buf0, kk0, m0-3, load b0
            short8 a[4];
            LOAD_B(0, bB0, b0); LOAD_A(0, aB0, 0);
            STG_BH(1, 1, ktA);
            MFMA_BLOCK(0, b0);
        }
        { // P2: buf0, kk1, m0-3, load b1 ; stage buf1.Aq1(ktA)
            short8 a[4];
            LOAD_B(0, bB1, b1); LOAD_A(0, aB1, 0);
            if (AFP32) { A_ISSUE(apreB, 0, ktB); A_PACK(apreA, 1, 1); }
            else       { STG_AQ(1, 1, ktA); }
            MFMA_BLOCK(0, b1);
        }
        { // P3: buf0, kk0, m4-7 ; stage buf0.Aq0(ktB)
            short8 a[4];
            LOAD_A(0, aB0, 1);
            if (AFP32) { A_ISSUE(apreA, 1, ktB); A_PACK(apreB, 0, 0); }
            else       { STG_AQ(0, 0, ktB); }
            MFMA_BLOCK(4, b0);
        }
        { // P4: buf0, kk1, m4-7  + gate
            short8 a[4];
            LOAD_A(0, aB1, 1);
            STG_BH(0, 0, ktB);
            GATEN();
            MFMA_BLOCK(4, b1);
        }
        { // P5: buf1, kk0, m0-3, load b0
            short8 a[4];
            LOAD_B(65536, bB0, b0); LOAD_A(65536, aB0, 0);
            STG_BH(0, 1, ktB);
            MFMA_BLOCK(0, b0);
        }
        { // P6: buf1, kk1, m0-3, load b1 ; stage buf0.Aq1(ktB)
            short8 a[4];
            LOAD_B(65536, bB1, b1); LOAD_A(65536, aB1, 0);
            if (AFP32) { A_ISSUE(apreB, 0, ktC); A_PACK(apreA, 0, 1); }
            else       { STG_AQ(0, 1, ktB); }
            MFMA_BLOCK(0, b1);
        }
        { // P7: buf1, kk0, m4-7 ; stage buf1.Aq0(ktC)
            short8 a[4];
            LOAD_A(65536, aB0, 1);
            if (AFP32) { A_ISSUE(apreA, 1, ktC); A_PACK(apreB, 1, 0); }
            else       { STG_AQ(1, 0, ktC); }
            MFMA_BLOCK(4, b0);
        }
        { // P8: buf1, kk1, m4-7  + gate
            short8 a[4];
            LOAD_A(65536, aB1, 1);
            STG_BH(1, 0, ktC);
            GATEN();
            MFMA_BLOCK(4, b1);
        }
    }
    // ---- peeled last iter (t=7): finish kt15 staging, no further prefetch ----
    {
        { short8 a[4]; LOAD_B(0, bB0, b0); LOAD_A(0, aB0, 0); STG_BH(1, 1, 15); MFMA_BLOCK(0, b0); }
        { short8 a[4]; LOAD_B(0, bB1, b1); LOAD_A(0, aB1, 0);
          if (AFP32) { A_PACK(apreA, 1, 1); } else { STG_AQ(1, 1, 15); }
          MFMA_BLOCK(0, b1); }
        { short8 a[4]; LOAD_A(0, aB0, 1); MFMA_BLOCK(4, b0); }
        { short8 a[4]; LOAD_A(0, aB1, 1); GATE0(); MFMA_BLOCK(4, b1); }
        { short8 a[4]; LOAD_B(65536, bB0, b0); LOAD_A(65536, aB0, 0); MFMA_BLOCK(0, b0); }
        { short8 a[4]; LOAD_B(65536, bB1, b1); LOAD_A(65536, aB1, 0); MFMA_BLOCK(0, b1); }
        { short8 a[4]; LOAD_A(65536, aB0, 1); MFMA_BLOCK(4, b0); }
        { short8 a[4]; LOAD_A(65536, aB1, 1); MFMA_BLOCK(4, b1); }
    }
#undef STG_AQ
#undef STG_BH
#undef A_ISSUE
#undef A_PACK
#undef GATEN
#undef GATE0
#undef MFMA_BLOCK
#undef LOAD_A
#undef LOAD_B

    // ---- epilogue: row = row0 + wr*128 + m*16 + lg*4 + j ; col = col0 + wc*64 + n*16 + lr ----
    const int r4 = lg * 4;
#pragma unroll
    for (int m = 0; m < 8; ++m) {
#pragma unroll
        for (int n = 0; n < 4; ++n) {
            long col = col0 + wc * 64 + n * 16 + lr;
            float bcol = bias[col];
            long R0 = row0 + wr * 128 + m * 16 + r4;
            if (MODE == 0) {
                unsigned short* O = (unsigned short*)out;
#pragma unroll
                for (int j = 0; j < 4; ++j) {
                    float v = acc[m][n][j] + bcol;
                    v = v > 0.f ? v + 1.f : __expf(v);
                    O[(R0 + j) * 1024 + col] = f2bf(v);
                }
            } else if (MODE == 1 || MODE == 2) {
                unsigned short* O = (unsigned short*)out;
                long nb = R0 >> 12;
                long s = R0 & 4095;
                short4v pack;
#pragma unroll
                for (int j = 0; j < 4; ++j) {
                    float v = acc[m][n][j] + bcol;
                    if (MODE == 1) v = v > 0.f ? v + 1.f : __expf(v);
                    pack[j] = (short)f2bf(v);
                }
                *(short4v*)(O + ((nb << 10) + col) * 4096 + s) = pack;
            } else {
                float* O = (float*)out;
#pragma unroll
                for (int j = 0; j < 4; ++j)
                    O[(R0 + j) * 1024 + col] = acc[m][n][j] + bcol;
            }
        }
    }
}

// ---------------- KV[n,h,m,d] = sum_s vT[n*1024+h*64+m][s] * Kt[n*1024+h*64+d][s] ----------------
// also Ksum[n*1024+h*64+d] = sum_s Kt[...][s].  Grid: 4*16*8 = 512 blocks (S chunks of 512).
__global__ __launch_bounds__(256) void kv_kernel(const unsigned short* __restrict__ Kt,
                                                 const unsigned short* __restrict__ vT,
                                                 float* __restrict__ KV,
                                                 float* __restrict__ Ksum) {
    int b = blockIdx.x;
    int sc = b & 7, h = (b >> 3) & 15, n = b >> 7;
    const int tid = threadIdx.x, lane = tid & 63, wave = tid >> 6;
    long base = ((long)(n * 1024 + h * 64)) * 4096 + sc * 512;
    const unsigned short* Kp = Kt + base;
    const unsigned short* Vp = vT + base;
    const int lr = lane & 15, lk = (lane >> 4) * 8;

    f32x4 acc[4] = {};
    for (int s0 = 0; s0 < 512; s0 += 32) {
        short8 a = *(const short8*)(Vp + (long)(wave * 16 + lr) * 4096 + s0 + lk);
#pragma unroll
        for (int d4 = 0; d4 < 4; ++d4) {
            short8 bb = *(const short8*)(Kp + (long)(d4 * 16 + lr) * 4096 + s0 + lk);
            acc[d4] = MFMA16(a, bb, acc[d4]);
        }
    }
    float* KVb = KV + (long)(n * 16 + h) * 4096;
#pragma unroll
    for (int d4 = 0; d4 < 4; ++d4)
#pragma unroll
        for (int j = 0; j < 4; ++j) {
            int m = wave * 16 + (lane >> 4) * 4 + j;
            int d = d4 * 16 + lr;
            atomicAdd(KVb + m * 64 + d, acc[d4][j]);
        }
    // Ksum partial: thread t sums 128 s for column d = t&63
    int d = tid & 63, part = tid >> 6;
    const unsigned short* kp2 = Kt + ((long)(n * 1024 + h * 64 + d)) * 4096 + sc * 512 + part * 128;
    float s = 0.f;
    for (int i = 0; i < 128; i += 8) {
        short8 v = *(const short8*)(kp2 + i);
#pragma unroll
        for (int e = 0; e < 8; ++e) s += bf2f((unsigned short)v[e]);
    }
    atomicAdd(Ksum + n * 1024 + h * 64 + d, s);
}

// ---------------- attn: V[n,l,h,m] = (sum_d Q[l,d]*KV[m,d]) / (Q[l,:]·Ksum + eps) ----------------
__global__ __launch_bounds__(256) void attn_kernel(const unsigned short* __restrict__ Qm,
                                                   const float* __restrict__ KV,
                                                   const float* __restrict__ Ksum,
                                                   unsigned short* __restrict__ Vbuf) {
    __shared__ unsigned short Qs[128 * 64];
    __shared__ unsigned short KVs[64 * 64];
    __shared__ float zin[128];
    __shared__ float ks[64];
    int b = blockIdx.x;
    int lc = b & 31, h = (b >> 5) & 15, n = b >> 9;
    int tid = threadIdx.x, lane = tid & 63, wave = tid >> 6;
    long l0 = (long)n * 4096 + lc * 128;

    const unsigned short* Qg = Qm + (l0 + (tid >> 3)) * 1024 + h * 64 + (tid & 7) * 8;
    char* QsB = (char*)Qs + (wave << 10);
#pragma unroll
    for (int it = 0; it < 4; ++it)
        async16(Qg + (long)it * 32 * 1024, QsB + it * 4096);

    const float* kvp = KV + (long)(n * 16 + h) * 4096;
    for (int i = tid * 4; i < 4096; i += 1024) {
        float4 v = *reinterpret_cast<const float4*>(kvp + i);
        short4v p;
        p[0] = (short)f2bf(v.x); p[1] = (short)f2bf(v.y);
        p[2] = (short)f2bf(v.z); p[3] = (short)f2bf(v.w);
        *(short4v*)(KVs + i) = p;
    }
    if (tid < 64) ks[tid] = Ksum[n * 1024 + h * 64 + tid];
    __syncthreads();

    if (tid < 128) {
        float den = 0.f;
        const unsigned short* qrow = Qs + tid * 64;
#pragma unroll
        for (int d = 0; d < 64; ++d) den += bf2f(qrow[d]) * ks[d];
        zin[tid] = 1.0f / (den + 1e-6f);
    }
    __syncthreads();

    const int lr = lane & 15, lk = (lane >> 4) * 8;
    f32x4 acc[2][4] = {};
#pragma unroll
    for (int kk = 0; kk < 2; ++kk) {
        short8 a0 = *(const short8*)(Qs + (wave * 32 + lr) * 64 + kk * 32 + lk);
        short8 a1 = *(const short8*)(Qs + (wave * 32 + 16 + lr) * 64 + kk * 32 + lk);
#pragma unroll
        for (int nn = 0; nn < 4; ++nn) {
            short8 bb = *(const short8*)(KVs + (nn * 16 + lr) * 64 + kk * 32 + lk);
            acc[0][nn] = MFMA16(a0, bb, acc[0][nn]);
            acc[1][nn] = MFMA16(a1, bb, acc[1][nn]);
        }
    }
#pragma unroll
    for (int mi = 0; mi < 2; ++mi)
#pragma unroll
        for (int nn = 0; nn < 4; ++nn)
#pragma unroll
            for (int j = 0; j < 4; ++j) {
                int rl = wave * 32 + mi * 16 + (lane >> 4) * 4 + j;
                int mcol = nn * 16 + lr;
                float v = acc[mi][nn][j] * zin[rl];
                Vbuf[(l0 + rl) * 1024 + h * 64 + mcol] = f2bf(v);
            }
}

extern "C" void kernel_launch(void* const* d_in, const int* in_sizes, int n_in,
                              void* d_out, int out_size, void* d_ws, size_t ws_size,
                              hipStream_t stream) {
    const float* queries = (const float*)d_in[0];
    const float* keys    = (const float*)d_in[1];
    const float* values  = (const float*)d_in[2];
    const float* Wq = (const float*)d_in[3];
    const float* bq = (const float*)d_in[4];
    const float* Wk = (const float*)d_in[5];
    const float* bk = (const float*)d_in[6];
    const float* Wv = (const float*)d_in[7];
    const float* bv = (const float*)d_in[8];
    const float* Wo = (const float*)d_in[9];
    const float* bo = (const float*)d_in[10];
    float* out = (float*)d_out;

    char* ws = (char*)d_ws;
    const size_t SZ = (size_t)16384 * 1024 * 2;  // 33.5 MB bf16 matrix
    const size_t WSZ = (size_t)1024 * 1024 * 2;  // 2 MB bf16 weight
    unsigned short* Wqb = (unsigned short*)(ws);
    unsigned short* Wkb = (unsigned short*)(ws + WSZ);
    unsigned short* Wvb = (unsigned short*)(ws + 2 * WSZ);
    unsigned short* Wob = (unsigned short*)(ws + 3 * WSZ);
    unsigned short* Qm   = (unsigned short*)(ws + 4 * WSZ);
    unsigned short* Kt   = (unsigned short*)(ws + 4 * WSZ + SZ);
    unsigned short* vT   = (unsigned short*)(ws + 4 * WSZ + 2 * SZ);
    unsigned short* Vbuf = (unsigned short*)(ws + 4 * WSZ + 3 * SZ);
    float* KVf = (float*)(ws + 4 * WSZ + 4 * SZ);
    float* Ksf = (float*)(ws + 4 * WSZ + 4 * SZ + 1048576);

    const int n4w = 1024 * 1024 / 4;
    cvt4_kernel<<<512, 256, 0, stream>>>(Wq, Wk, Wv, Wo, Wqb, Wkb, Wvb, Wob, n4w);

    gemm8p<0, 1><<<256, 512, 0, stream>>>(queries, Wqb, bq, Qm);
    gemm8p<1, 1><<<256, 512, 0, stream>>>(keys, Wkb, bk, Kt);
    gemm8p<2, 1><<<256, 512, 0, stream>>>(values, Wvb, bv, vT);

    hipMemsetAsync(KVf, 0, 1048576 + 16384, stream);
    kv_kernel<<<512, 256, 0, stream>>>(Kt, vT, KVf, Ksf);
    attn_kernel<<<2048, 256, 0, stream>>>(Qm, KVf, Ksf, Vbuf);

    gemm8p<3, 0><<<256, 512, 0, stream>>>(Vbuf, Wob, bo, out);
}

// Round 8
// 257.047 us; speedup vs baseline: 1.1278x; 1.1278x over previous
//
#include <hip/hip_runtime.h>
#include <hip/hip_bf16.h>

typedef __attribute__((ext_vector_type(8))) short short8;
typedef __attribute__((ext_vector_type(4))) short short4v;
typedef __attribute__((ext_vector_type(4))) float f32x4;

#define MFMA16(a, b, c) __builtin_amdgcn_mfma_f32_16x16x32_bf16(a, b, c, 0, 0, 0)

__device__ __forceinline__ unsigned short f2bf(float f) {
    unsigned int u = __float_as_uint(f);
    unsigned int r = u + 0x7fffu + ((u >> 16) & 1u);
    return (unsigned short)(r >> 16);
}
__device__ __forceinline__ float bf2f(unsigned short h) {
    return __uint_as_float(((unsigned int)h) << 16);
}

__device__ __forceinline__ void async16(const void* g, void* l) {
    __builtin_amdgcn_global_load_lds(
        (const __attribute__((address_space(1))) unsigned int*)g,
        (__attribute__((address_space(3))) unsigned int*)l, 16, 0, 0);
}

#define S_BARRIER() asm volatile("s_barrier" ::: "memory")
#define SCHED_FENCE() __builtin_amdgcn_sched_barrier(0)

// ---------------- merged fp32 -> bf16 conversion: q, k, v, and 4 weights, one launch ----
__global__ __launch_bounds__(256) void cvt_all(const float* __restrict__ q,
                                               const float* __restrict__ k,
                                               const float* __restrict__ v,
                                               const float* __restrict__ Wq,
                                               const float* __restrict__ Wk,
                                               const float* __restrict__ Wv,
                                               const float* __restrict__ Wo,
                                               unsigned short* __restrict__ qb,
                                               unsigned short* __restrict__ kb,
                                               unsigned short* __restrict__ vb,
                                               unsigned short* __restrict__ Wqb,
                                               unsigned short* __restrict__ Wkb,
                                               unsigned short* __restrict__ Wvb,
                                               unsigned short* __restrict__ Wob) {
    int b = blockIdx.x;
    const float* in;
    unsigned short* out;
    int lb, nb, n4;
    if (b < 6144) {
        int s = b >> 11;                 // 0..2
        lb = b & 2047; nb = 2048; n4 = 4194304;  // 16M elements / 4
        in = s == 0 ? q : s == 1 ? k : v;
        out = s == 0 ? qb : s == 1 ? kb : vb;
    } else {
        int s = b - 6144;                // 0..511
        int w = s >> 7;                  // 0..3
        lb = s & 127; nb = 128; n4 = 262144;     // 1M elements / 4
        in = w == 0 ? Wq : w == 1 ? Wk : w == 2 ? Wv : Wo;
        out = w == 0 ? Wqb : w == 1 ? Wkb : w == 2 ? Wvb : Wob;
    }
    for (int i = lb * 256 + threadIdx.x; i < n4; i += nb * 256) {
        float4 vv = reinterpret_cast<const float4*>(in)[i];
        short4v p;
        p[0] = (short)f2bf(vv.x); p[1] = (short)f2bf(vv.y);
        p[2] = (short)f2bf(vv.z); p[3] = (short)f2bf(vv.w);
        reinterpret_cast<short4v*>(out)[i] = p;
    }
}

// ---------------- 8-phase GEMM body (R6-verified): C[M,1024] = A @ B^T + bias ----------
// BM=BN=256, BK=64, 2 K-tiles/iter, 8 waves 2Mx4N, 2x64KB LDS, 3-bit XOR swizzle
// (0 bank conflicts), counted vmcnt(4) gates only at phases 4 & 8.
// mode 0: elu+1, bf16 out, normal layout [M][1024]
// mode 1: elu+1, bf16 out, transposed [n*1024+col][4096]
// mode 2: plain, bf16 out, transposed
// mode 3: plain, fp32 out, normal layout
__device__ __forceinline__ void gemm_body(const unsigned short* __restrict__ A,
                                          const unsigned short* __restrict__ B,
                                          const float* __restrict__ bias,
                                          void* __restrict__ out,
                                          int mode, char* lds, int bid) {
    const int tid = threadIdx.x;             // 0..511
    const int lane = tid & 63, wid = tid >> 6;
    const int wr = wid >> 2, wc = wid & 3;   // wave out: rows wr*128, cols wc*64
    const int lr = lane & 15, lg = lane >> 4;

    // XCD-aware bijective swizzle (per-segment grid of 256)
    const int swz = (bid & 7) * 32 + (bid >> 3);
    const int bm = swz >> 2, bn = swz & 3;
    const long row0 = (long)bm * 256;
    const long col0 = (long)bn * 256;

    // ---- staging sources (pre-swizzled; LDS dest linear) ----
    const unsigned short* srcA[2];
    const unsigned short* srcB[2];
    int dstOff[2];
#pragma unroll
    for (int g = 0; g < 2; ++g) {
        int s = g * 512 + tid;
        int pr = s >> 3;
        int dc = (s & 7) ^ (pr & 7);
        srcA[g] = A + (row0 + (pr & 63) + 128 * (pr >> 6)) * 1024 + dc * 8;
        srcB[g] = B + (col0 + pr) * 1024 + dc * 8;
        dstOff[g] = s * 16;
    }

#define STG_AQ(BB, Q, KT) do {                                                  \
        async16(srcA[0] + (Q) * 65536 + (KT) * 64,                              \
                lds + (BB) * 65536 + (Q) * 16384 + dstOff[0]);                  \
        async16(srcA[1] + (Q) * 65536 + (KT) * 64,                              \
                lds + (BB) * 65536 + (Q) * 16384 + dstOff[1]); } while (0)
#define STG_BH(BB, H, KT) do {                                                  \
        async16(srcB[0] + (H) * 131072 + (KT) * 64,                             \
                lds + (BB) * 65536 + 32768 + (H) * 16384 + dstOff[0]);          \
        async16(srcB[1] + (H) * 131072 + (KT) * 64,                             \
                lds + (BB) * 65536 + 32768 + (H) * 16384 + dstOff[1]); } while (0)

    const int ch0 = (((0 * 4 + lg) ^ (lr & 7)) << 4);
    const int ch1 = (((1 * 4 + lg) ^ (lr & 7)) << 4);
    const int aB0 = (64 * wr + lr) * 128 + ch0;
    const int aB1 = (64 * wr + lr) * 128 + ch1;
    const int bB0 = 32768 + (wc >> 1) * 16384 + ((wc & 1) * 64 + lr) * 128 + ch0;
    const int bB1 = 32768 + (wc >> 1) * 16384 + ((wc & 1) * 64 + lr) * 128 + ch1;

    f32x4 acc[8][4] = {};
    short8 b0[4], b1[4];

#define GATE4() do { asm volatile("s_waitcnt vmcnt(4)" ::: "memory"); SCHED_FENCE(); } while (0)
#define GATE0() do { asm volatile("s_waitcnt vmcnt(0)" ::: "memory"); SCHED_FENCE(); } while (0)
#define MFMA_BLOCK(MB, BV) do {                                                 \
        S_BARRIER();                                                            \
        asm volatile("s_waitcnt lgkmcnt(0)" ::: "memory");                      \
        SCHED_FENCE();                                                          \
        __builtin_amdgcn_s_setprio(1);                                          \
        _Pragma("unroll") for (int m = 0; m < 4; ++m)                           \
            _Pragma("unroll") for (int n = 0; n < 4; ++n)                       \
                acc[(MB) + m][n] = MFMA16(a[m], BV[n], acc[(MB) + m][n]);       \
        __builtin_amdgcn_s_setprio(0);                                          \
        SCHED_FENCE();                                                          \
        S_BARRIER(); } while (0)
#define LOAD_A(BUFB, ABASE, Q) do {                                             \
        _Pragma("unroll") for (int m = 0; m < 4; ++m)                           \
            a[m] = *(const short8*)(lds + (BUFB) + (Q) * 16384 + (ABASE) + m * 2048); } while (0)
#define LOAD_B(BUFB, BBASE, BV) do {                                            \
        _Pragma("unroll") for (int n = 0; n < 4; ++n)                           \
            BV[n] = *(const short8*)(lds + (BUFB) + (BBASE) + n * 2048); } while (0)

    // ---- prologue: kt0 -> buf0 (all 4 halves), kt1 -> buf1 (Aq0,B0) ----
    STG_AQ(0, 0, 0); STG_BH(0, 0, 0); STG_BH(0, 1, 0); STG_AQ(0, 1, 0);
    STG_AQ(1, 0, 1); STG_BH(1, 0, 1);
    GATE4();
    S_BARRIER();

#pragma unroll 1
    for (int t = 0; t < 7; ++t) {
        const int ktA = 2 * t + 1, ktB = 2 * t + 2, ktC = 2 * t + 3;
        { short8 a[4]; LOAD_B(0, bB0, b0); LOAD_A(0, aB0, 0); STG_BH(1, 1, ktA); MFMA_BLOCK(0, b0); }
        { short8 a[4]; LOAD_B(0, bB1, b1); LOAD_A(0, aB1, 0); STG_AQ(1, 1, ktA); MFMA_BLOCK(0, b1); }
        { short8 a[4]; LOAD_A(0, aB0, 1); STG_AQ(0, 0, ktB); MFMA_BLOCK(4, b0); }
        { short8 a[4]; LOAD_A(0, aB1, 1); STG_BH(0, 0, ktB); GATE4(); MFMA_BLOCK(4, b1); }
        { short8 a[4]; LOAD_B(65536, bB0, b0); LOAD_A(65536, aB0, 0); STG_BH(0, 1, ktB); MFMA_BLOCK(0, b0); }
        { short8 a[4]; LOAD_B(65536, bB1, b1); LOAD_A(65536, aB1, 0); STG_AQ(0, 1, ktB); MFMA_BLOCK(0, b1); }
        { short8 a[4]; LOAD_A(65536, aB0, 1); STG_AQ(1, 0, ktC); MFMA_BLOCK(4, b0); }
        { short8 a[4]; LOAD_A(65536, aB1, 1); STG_BH(1, 0, ktC); GATE4(); MFMA_BLOCK(4, b1); }
    }
    // ---- peeled last iter (t=7) ----
    {
        { short8 a[4]; LOAD_B(0, bB0, b0); LOAD_A(0, aB0, 0); STG_BH(1, 1, 15); MFMA_BLOCK(0, b0); }
        { short8 a[4]; LOAD_B(0, bB1, b1); LOAD_A(0, aB1, 0); STG_AQ(1, 1, 15); MFMA_BLOCK(0, b1); }
        { short8 a[4]; LOAD_A(0, aB0, 1); MFMA_BLOCK(4, b0); }
        { short8 a[4]; LOAD_A(0, aB1, 1); GATE0(); MFMA_BLOCK(4, b1); }
        { short8 a[4]; LOAD_B(65536, bB0, b0); LOAD_A(65536, aB0, 0); MFMA_BLOCK(0, b0); }
        { short8 a[4]; LOAD_B(65536, bB1, b1); LOAD_A(65536, aB1, 0); MFMA_BLOCK(0, b1); }
        { short8 a[4]; LOAD_A(65536, aB0, 1); MFMA_BLOCK(4, b0); }
        { short8 a[4]; LOAD_A(65536, aB1, 1); MFMA_BLOCK(4, b1); }
    }
#undef STG_AQ
#undef STG_BH
#undef GATE4
#undef GATE0
#undef MFMA_BLOCK
#undef LOAD_A
#undef LOAD_B

    // ---- epilogue ----
    const int r4 = lg * 4;
#pragma unroll
    for (int m = 0; m < 8; ++m) {
#pragma unroll
        for (int n = 0; n < 4; ++n) {
            long col = col0 + wc * 64 + n * 16 + lr;
            float bcol = bias[col];
            long R0 = row0 + wr * 128 + m * 16 + r4;
            if (mode == 0) {
                unsigned short* O = (unsigned short*)out;
#pragma unroll
                for (int j = 0; j < 4; ++j) {
                    float v = acc[m][n][j] + bcol;
                    v = v > 0.f ? v + 1.f : __expf(v);
                    O[(R0 + j) * 1024 + col] = f2bf(v);
                }
            } else if (mode == 1 || mode == 2) {
                unsigned short* O = (unsigned short*)out;
                long nb = R0 >> 12;
                long s = R0 & 4095;
                short4v pack;
#pragma unroll
                for (int j = 0; j < 4; ++j) {
                    float v = acc[m][n][j] + bcol;
                    if (mode == 1) v = v > 0.f ? v + 1.f : __expf(v);
                    pack[j] = (short)f2bf(v);
                }
                *(short4v*)(O + ((nb << 10) + col) * 4096 + s) = pack;
            } else {
                float* O = (float*)out;
#pragma unroll
                for (int j = 0; j < 4; ++j)
                    O[(R0 + j) * 1024 + col] = acc[m][n][j] + bcol;
            }
        }
    }
}

// ---- merged Q/K/V projection: 768 blocks, segment = blockIdx.x>>8 ----
__global__ __launch_bounds__(512, 1) void proj_gemm(const unsigned short* __restrict__ qb,
                                                    const unsigned short* __restrict__ kb,
                                                    const unsigned short* __restrict__ vb,
                                                    const unsigned short* __restrict__ Wqb,
                                                    const unsigned short* __restrict__ Wkb,
                                                    const unsigned short* __restrict__ Wvb,
                                                    const float* __restrict__ bq,
                                                    const float* __restrict__ bk,
                                                    const float* __restrict__ bv,
                                                    unsigned short* __restrict__ Qm,
                                                    unsigned short* __restrict__ Kt,
                                                    unsigned short* __restrict__ vT) {
    __shared__ __align__(16) char lds[131072];
    int seg = blockIdx.x >> 8;
    int bid = blockIdx.x & 255;
    const unsigned short* A = seg == 0 ? qb : seg == 1 ? kb : vb;
    const unsigned short* B = seg == 0 ? Wqb : seg == 1 ? Wkb : Wvb;
    const float* bias = seg == 0 ? bq : seg == 1 ? bk : bv;
    void* out = seg == 0 ? (void*)Qm : seg == 1 ? (void*)Kt : (void*)vT;
    gemm_body(A, B, bias, out, seg, lds, bid);   // mode 0/1/2 == seg
}

// ---- output projection: 256 blocks, mode 3 ----
__global__ __launch_bounds__(512, 1) void out_gemm(const unsigned short* __restrict__ Vbuf,
                                                   const unsigned short* __restrict__ Wob,
                                                   const float* __restrict__ bo,
                                                   float* __restrict__ out) {
    __shared__ __align__(16) char lds[131072];
    gemm_body(Vbuf, Wob, bo, out, 3, lds, blockIdx.x);
}

// ---------------- KV[n,h,m,d] = sum_s vT[n*1024+h*64+m][s] * Kt[n*1024+h*64+d][s] ----------------
__global__ __launch_bounds__(256) void kv_kernel(const unsigned short* __restrict__ Kt,
                                                 const unsigned short* __restrict__ vT,
                                                 float* __restrict__ KV,
                                                 float* __restrict__ Ksum) {
    int b = blockIdx.x;
    int sc = b & 7, h = (b >> 3) & 15, n = b >> 7;
    const int tid = threadIdx.x, lane = tid & 63, wave = tid >> 6;
    long base = ((long)(n * 1024 + h * 64)) * 4096 + sc * 512;
    const unsigned short* Kp = Kt + base;
    const unsigned short* Vp = vT + base;
    const int lr = lane & 15, lk = (lane >> 4) * 8;

    f32x4 acc[4] = {};
    for (int s0 = 0; s0 < 512; s0 += 32) {
        short8 a = *(const short8*)(Vp + (long)(wave * 16 + lr) * 4096 + s0 + lk);
#pragma unroll
        for (int d4 = 0; d4 < 4; ++d4) {
            short8 bb = *(const short8*)(Kp + (long)(d4 * 16 + lr) * 4096 + s0 + lk);
            acc[d4] = MFMA16(a, bb, acc[d4]);
        }
    }
    float* KVb = KV + (long)(n * 16 + h) * 4096;
#pragma unroll
    for (int d4 = 0; d4 < 4; ++d4)
#pragma unroll
        for (int j = 0; j < 4; ++j) {
            int m = wave * 16 + (lane >> 4) * 4 + j;
            int d = d4 * 16 + lr;
            atomicAdd(KVb + m * 64 + d, acc[d4][j]);
        }
    int d = tid & 63, part = tid >> 6;
    const unsigned short* kp2 = Kt + ((long)(n * 1024 + h * 64 + d)) * 4096 + sc * 512 + part * 128;
    float s = 0.f;
    for (int i = 0; i < 128; i += 8) {
        short8 v = *(const short8*)(kp2 + i);
#pragma unroll
        for (int e = 0; e < 8; ++e) s += bf2f((unsigned short)v[e]);
    }
    atomicAdd(Ksum + n * 1024 + h * 64 + d, s);
}

// ---------------- attn: V[n,l,h,m] = (sum_d Q[l,d]*KV[m,d]) / (Q[l,:]·Ksum + eps) ----------------
__global__ __launch_bounds__(256) void attn_kernel(const unsigned short* __restrict__ Qm,
                                                   const float* __restrict__ KV,
                                                   const float* __restrict__ Ksum,
                                                   unsigned short* __restrict__ Vbuf) {
    __shared__ unsigned short Qs[128 * 64];
    __shared__ unsigned short KVs[64 * 64];
    __shared__ float zin[128];
    __shared__ float ks[64];
    int b = blockIdx.x;
    int lc = b & 31, h = (b >> 5) & 15, n = b >> 9;
    int tid = threadIdx.x, lane = tid & 63, wave = tid >> 6;
    long l0 = (long)n * 4096 + lc * 128;

    const unsigned short* Qg = Qm + (l0 + (tid >> 3)) * 1024 + h * 64 + (tid & 7) * 8;
    char* QsB = (char*)Qs + (wave << 10);
#pragma unroll
    for (int it = 0; it < 4; ++it)
        async16(Qg + (long)it * 32 * 1024, QsB + it * 4096);

    const float* kvp = KV + (long)(n * 16 + h) * 4096;
    for (int i = tid * 4; i < 4096; i += 1024) {
        float4 v = *reinterpret_cast<const float4*>(kvp + i);
        short4v p;
        p[0] = (short)f2bf(v.x); p[1] = (short)f2bf(v.y);
        p[2] = (short)f2bf(v.z); p[3] = (short)f2bf(v.w);
        *(short4v*)(KVs + i) = p;
    }
    if (tid < 64) ks[tid] = Ksum[n * 1024 + h * 64 + tid];
    __syncthreads();

    // wave-parallel normalizer: 2 threads per row, 32 d each, shfl_xor combine
    {
        int row = tid >> 1, half = tid & 1;
        float den = 0.f;
        const unsigned short* qrow = Qs + row * 64 + half * 32;
#pragma unroll
        for (int d = 0; d < 32; ++d) den += bf2f(qrow[d]) * ks[half * 32 + d];
        den += __shfl_xor(den, 1, 64);
        if (half == 0) zin[row] = 1.0f / (den + 1e-6f);
    }
    __syncthreads();

    const int lr = lane & 15, lk = (lane >> 4) * 8;
    f32x4 acc[2][4] = {};
#pragma unroll
    for (int kk = 0; kk < 2; ++kk) {
        short8 a0 = *(const short8*)(Qs + (wave * 32 + lr) * 64 + kk * 32 + lk);
        short8 a1 = *(const short8*)(Qs + (wave * 32 + 16 + lr) * 64 + kk * 32 + lk);
#pragma unroll
        for (int nn = 0; nn < 4; ++nn) {
            short8 bb = *(const short8*)(KVs + (nn * 16 + lr) * 64 + kk * 32 + lk);
            acc[0][nn] = MFMA16(a0, bb, acc[0][nn]);
            acc[1][nn] = MFMA16(a1, bb, acc[1][nn]);
        }
    }
#pragma unroll
    for (int mi = 0; mi < 2; ++mi)
#pragma unroll
        for (int nn = 0; nn < 4; ++nn)
#pragma unroll
            for (int j = 0; j < 4; ++j) {
                int rl = wave * 32 + mi * 16 + (lane >> 4) * 4 + j;
                int mcol = nn * 16 + lr;
                float v = acc[mi][nn][j] * zin[rl];
                Vbuf[(l0 + rl) * 1024 + h * 64 + mcol] = f2bf(v);
            }
}

extern "C" void kernel_launch(void* const* d_in, const int* in_sizes, int n_in,
                              void* d_out, int out_size, void* d_ws, size_t ws_size,
                              hipStream_t stream) {
    const float* queries = (const float*)d_in[0];
    const float* keys    = (const float*)d_in[1];
    const float* values  = (const float*)d_in[2];
    const float* Wq = (const float*)d_in[3];
    const float* bq = (const float*)d_in[4];
    const float* Wk = (const float*)d_in[5];
    const float* bk = (const float*)d_in[6];
    const float* Wv = (const float*)d_in[7];
    const float* bv = (const float*)d_in[8];
    const float* Wo = (const float*)d_in[9];
    const float* bo = (const float*)d_in[10];
    float* out = (float*)d_out;

    char* ws = (char*)d_ws;
    const size_t SZ = (size_t)16384 * 1024 * 2;  // 33.5 MB bf16 matrix
    const size_t WSZ = (size_t)1024 * 1024 * 2;  // 2 MB bf16 weight
    unsigned short* qb  = (unsigned short*)(ws);
    unsigned short* kb  = (unsigned short*)(ws + SZ);
    unsigned short* vb  = (unsigned short*)(ws + 2 * SZ);
    unsigned short* Wqb = (unsigned short*)(ws + 3 * SZ);
    unsigned short* Wkb = (unsigned short*)(ws + 3 * SZ + WSZ);
    unsigned short* Wvb = (unsigned short*)(ws + 3 * SZ + 2 * WSZ);
    unsigned short* Wob = (unsigned short*)(ws + 3 * SZ + 3 * WSZ);
    unsigned short* Qm  = (unsigned short*)(ws + 3 * SZ + 4 * WSZ);
    unsigned short* Kt  = (unsigned short*)(ws + 4 * SZ + 4 * WSZ);
    unsigned short* vT  = (unsigned short*)(ws + 5 * SZ + 4 * WSZ);
    float* KVf = (float*)(ws + 6 * SZ + 4 * WSZ);
    float* Ksf = (float*)(ws + 6 * SZ + 4 * WSZ + 1048576);
    unsigned short* Vbuf = qb;  // alias: qb dead after projections

    cvt_all<<<6656, 256, 0, stream>>>(queries, keys, values, Wq, Wk, Wv, Wo,
                                      qb, kb, vb, Wqb, Wkb, Wvb, Wob);

    proj_gemm<<<768, 512, 0, stream>>>(qb, kb, vb, Wqb, Wkb, Wvb, bq, bk, bv, Qm, Kt, vT);

    hipMemsetAsync(KVf, 0, 1048576 + 16384, stream);
    kv_kernel<<<512, 256, 0, stream>>>(Kt, vT, KVf, Ksf);
    attn_kernel<<<2048, 256, 0, stream>>>(Qm, KVf, Ksf, Vbuf);

    out_gemm<<<256, 512, 0, stream>>>(Vbuf, Wob, bo, out);
}

// Round 9
// 251.549 us; speedup vs baseline: 1.1524x; 1.0219x over previous
//
#include <hip/hip_runtime.h>
#include <hip/hip_bf16.h>

typedef __attribute__((ext_vector_type(8))) short short8;
typedef __attribute__((ext_vector_type(4))) short short4v;
typedef __attribute__((ext_vector_type(4))) float f32x4;

#define MFMA16(a, b, c) __builtin_amdgcn_mfma_f32_16x16x32_bf16(a, b, c, 0, 0, 0)

__device__ __forceinline__ unsigned short f2bf(float f) {
    unsigned int u = __float_as_uint(f);
    unsigned int r = u + 0x7fffu + ((u >> 16) & 1u);
    return (unsigned short)(r >> 16);
}
__device__ __forceinline__ float bf2f(unsigned short h) {
    return __uint_as_float(((unsigned int)h) << 16);
}
__device__ __forceinline__ unsigned int pk2(float lo, float hi) {
    return (unsigned int)f2bf(lo) | ((unsigned int)f2bf(hi) << 16);
}

__device__ __forceinline__ void async16(const void* g, void* l) {
    __builtin_amdgcn_global_load_lds(
        (const __attribute__((address_space(1))) unsigned int*)g,
        (__attribute__((address_space(3))) unsigned int*)l, 16, 0, 0);
}

#define S_BARRIER() asm volatile("s_barrier" ::: "memory")
#define SCHED_FENCE() __builtin_amdgcn_sched_barrier(0)

// ---------------- merged fp32 -> bf16 conversion: q, k, v, and 4 weights, one launch ----
// 32B read / 16B write per lane per iter.
__global__ __launch_bounds__(256) void cvt_all(const float* __restrict__ q,
                                               const float* __restrict__ k,
                                               const float* __restrict__ v,
                                               const float* __restrict__ Wq,
                                               const float* __restrict__ Wk,
                                               const float* __restrict__ Wv,
                                               const float* __restrict__ Wo,
                                               unsigned short* __restrict__ qb,
                                               unsigned short* __restrict__ kb,
                                               unsigned short* __restrict__ vb,
                                               unsigned short* __restrict__ Wqb,
                                               unsigned short* __restrict__ Wkb,
                                               unsigned short* __restrict__ Wvb,
                                               unsigned short* __restrict__ Wob) {
    int b = blockIdx.x;
    const float* in;
    unsigned short* out;
    int lb, nb, n8;
    if (b < 6144) {
        int s = b >> 11;                 // 0..2
        lb = b & 2047; nb = 2048; n8 = 2097152;  // 16M elements / 8
        in = s == 0 ? q : s == 1 ? k : v;
        out = s == 0 ? qb : s == 1 ? kb : vb;
    } else {
        int s = b - 6144;                // 0..511
        int w = s >> 7;                  // 0..3
        lb = s & 127; nb = 128; n8 = 131072;     // 1M elements / 8
        in = w == 0 ? Wq : w == 1 ? Wk : w == 2 ? Wv : Wo;
        out = w == 0 ? Wqb : w == 1 ? Wkb : w == 2 ? Wvb : Wob;
    }
    for (int i = lb * 256 + threadIdx.x; i < n8; i += nb * 256) {
        float4 v0 = reinterpret_cast<const float4*>(in)[2 * i];
        float4 v1 = reinterpret_cast<const float4*>(in)[2 * i + 1];
        uint4 p;
        p.x = pk2(v0.x, v0.y); p.y = pk2(v0.z, v0.w);
        p.z = pk2(v1.x, v1.y); p.w = pk2(v1.z, v1.w);
        reinterpret_cast<uint4*>(out)[i] = p;
    }
}

// ---------------- 8-phase GEMM body (R6-verified): C[M,1024] = A @ B^T + bias ----------
// BM=BN=256, BK=64, 2 K-tiles/iter, 8 waves 2Mx4N, 2x64KB LDS, 3-bit XOR swizzle
// (0 bank conflicts), counted vmcnt(4) gates only at phases 4 & 8.
// mode 0: elu+1, bf16 out, normal layout [M][1024]        -- LDS-staged coalesced stores
// mode 1: elu+1, bf16 out, transposed [n*1024+col][4096]
// mode 2: plain, bf16 out, transposed
// mode 3: plain, fp32 out, normal layout                  -- LDS-staged coalesced stores
__device__ __forceinline__ void gemm_body(const unsigned short* __restrict__ A,
                                          const unsigned short* __restrict__ B,
                                          const float* __restrict__ bias,
                                          void* __restrict__ out,
                                          int mode, char* lds, int bid) {
    const int tid = threadIdx.x;             // 0..511
    const int lane = tid & 63, wid = tid >> 6;
    const int wr = wid >> 2, wc = wid & 3;   // wave out: rows wr*128, cols wc*64
    const int lr = lane & 15, lg = lane >> 4;

    // XCD-aware bijective swizzle (per-segment grid of 256)
    const int swz = (bid & 7) * 32 + (bid >> 3);
    const int bm = swz >> 2, bn = swz & 3;
    const long row0 = (long)bm * 256;
    const long col0 = (long)bn * 256;

    // ---- staging sources (pre-swizzled; LDS dest linear) ----
    const unsigned short* srcA[2];
    const unsigned short* srcB[2];
    int dstOff[2];
#pragma unroll
    for (int g = 0; g < 2; ++g) {
        int s = g * 512 + tid;
        int pr = s >> 3;
        int dc = (s & 7) ^ (pr & 7);
        srcA[g] = A + (row0 + (pr & 63) + 128 * (pr >> 6)) * 1024 + dc * 8;
        srcB[g] = B + (col0 + pr) * 1024 + dc * 8;
        dstOff[g] = s * 16;
    }

#define STG_AQ(BB, Q, KT) do {                                                  \
        async16(srcA[0] + (Q) * 65536 + (KT) * 64,                              \
                lds + (BB) * 65536 + (Q) * 16384 + dstOff[0]);                  \
        async16(srcA[1] + (Q) * 65536 + (KT) * 64,                              \
                lds + (BB) * 65536 + (Q) * 16384 + dstOff[1]); } while (0)
#define STG_BH(BB, H, KT) do {                                                  \
        async16(srcB[0] + (H) * 131072 + (KT) * 64,                             \
                lds + (BB) * 65536 + 32768 + (H) * 16384 + dstOff[0]);          \
        async16(srcB[1] + (H) * 131072 + (KT) * 64,                             \
                lds + (BB) * 65536 + 32768 + (H) * 16384 + dstOff[1]); } while (0)

    const int ch0 = (((0 * 4 + lg) ^ (lr & 7)) << 4);
    const int ch1 = (((1 * 4 + lg) ^ (lr & 7)) << 4);
    const int aB0 = (64 * wr + lr) * 128 + ch0;
    const int aB1 = (64 * wr + lr) * 128 + ch1;
    const int bB0 = 32768 + (wc >> 1) * 16384 + ((wc & 1) * 64 + lr) * 128 + ch0;
    const int bB1 = 32768 + (wc >> 1) * 16384 + ((wc & 1) * 64 + lr) * 128 + ch1;

    f32x4 acc[8][4] = {};
    short8 b0[4], b1[4];

#define GATE4() do { asm volatile("s_waitcnt vmcnt(4)" ::: "memory"); SCHED_FENCE(); } while (0)
#define GATE0() do { asm volatile("s_waitcnt vmcnt(0)" ::: "memory"); SCHED_FENCE(); } while (0)
#define MFMA_BLOCK(MB, BV) do {                                                 \
        S_BARRIER();                                                            \
        asm volatile("s_waitcnt lgkmcnt(0)" ::: "memory");                      \
        SCHED_FENCE();                                                          \
        __builtin_amdgcn_s_setprio(1);                                          \
        _Pragma("unroll") for (int m = 0; m < 4; ++m)                           \
            _Pragma("unroll") for (int n = 0; n < 4; ++n)                       \
                acc[(MB) + m][n] = MFMA16(a[m], BV[n], acc[(MB) + m][n]);       \
        __builtin_amdgcn_s_setprio(0);                                          \
        SCHED_FENCE();                                                          \
        S_BARRIER(); } while (0)
#define LOAD_A(BUFB, ABASE, Q) do {                                             \
        _Pragma("unroll") for (int m = 0; m < 4; ++m)                           \
            a[m] = *(const short8*)(lds + (BUFB) + (Q) * 16384 + (ABASE) + m * 2048); } while (0)
#define LOAD_B(BUFB, BBASE, BV) do {                                            \
        _Pragma("unroll") for (int n = 0; n < 4; ++n)                           \
            BV[n] = *(const short8*)(lds + (BUFB) + (BBASE) + n * 2048); } while (0)

    // ---- prologue: kt0 -> buf0 (all 4 halves), kt1 -> buf1 (Aq0,B0) ----
    STG_AQ(0, 0, 0); STG_BH(0, 0, 0); STG_BH(0, 1, 0); STG_AQ(0, 1, 0);
    STG_AQ(1, 0, 1); STG_BH(1, 0, 1);
    GATE4();
    S_BARRIER();

#pragma unroll 1
    for (int t = 0; t < 7; ++t) {
        const int ktA = 2 * t + 1, ktB = 2 * t + 2, ktC = 2 * t + 3;
        { short8 a[4]; LOAD_B(0, bB0, b0); LOAD_A(0, aB0, 0); STG_BH(1, 1, ktA); MFMA_BLOCK(0, b0); }
        { short8 a[4]; LOAD_B(0, bB1, b1); LOAD_A(0, aB1, 0); STG_AQ(1, 1, ktA); MFMA_BLOCK(0, b1); }
        { short8 a[4]; LOAD_A(0, aB0, 1); STG_AQ(0, 0, ktB); MFMA_BLOCK(4, b0); }
        { short8 a[4]; LOAD_A(0, aB1, 1); STG_BH(0, 0, ktB); GATE4(); MFMA_BLOCK(4, b1); }
        { short8 a[4]; LOAD_B(65536, bB0, b0); LOAD_A(65536, aB0, 0); STG_BH(0, 1, ktB); MFMA_BLOCK(0, b0); }
        { short8 a[4]; LOAD_B(65536, bB1, b1); LOAD_A(65536, aB1, 0); STG_AQ(0, 1, ktB); MFMA_BLOCK(0, b1); }
        { short8 a[4]; LOAD_A(65536, aB0, 1); STG_AQ(1, 0, ktC); MFMA_BLOCK(4, b0); }
        { short8 a[4]; LOAD_A(65536, aB1, 1); STG_BH(1, 0, ktC); GATE4(); MFMA_BLOCK(4, b1); }
    }
    // ---- peeled last iter (t=7) ----
    {
        { short8 a[4]; LOAD_B(0, bB0, b0); LOAD_A(0, aB0, 0); STG_BH(1, 1, 15); MFMA_BLOCK(0, b0); }
        { short8 a[4]; LOAD_B(0, bB1, b1); LOAD_A(0, aB1, 0); STG_AQ(1, 1, 15); MFMA_BLOCK(0, b1); }
        { short8 a[4]; LOAD_A(0, aB0, 1); MFMA_BLOCK(4, b0); }
        { short8 a[4]; LOAD_A(0, aB1, 1); GATE0(); MFMA_BLOCK(4, b1); }
        { short8 a[4]; LOAD_B(65536, bB0, b0); LOAD_A(65536, aB0, 0); MFMA_BLOCK(0, b0); }
        { short8 a[4]; LOAD_B(65536, bB1, b1); LOAD_A(65536, aB1, 0); MFMA_BLOCK(0, b1); }
        { short8 a[4]; LOAD_A(65536, aB0, 1); MFMA_BLOCK(4, b0); }
        { short8 a[4]; LOAD_A(65536, aB1, 1); MFMA_BLOCK(4, b1); }
    }
#undef STG_AQ
#undef STG_BH
#undef GATE4
#undef GATE0
#undef MFMA_BLOCK
#undef LOAD_A
#undef LOAD_B

    // ---- epilogue ----
    const int r4 = lg * 4;
    if (mode == 0 || mode == 3) {
        // Per-wave LDS staging: [16 rows][64 cols] f32, row stride 68 words (bank-spread),
        // then fully-coalesced 16B stores. Main-loop LDS is dead; regions are per-wave
        // (no barrier needed: wave-internal ds ordering via lgkmcnt).
        char* ep = lds + wid * 4608;
#pragma unroll
        for (int m = 0; m < 8; ++m) {
#pragma unroll
            for (int n = 0; n < 4; ++n) {
                float bcol = bias[col0 + wc * 64 + n * 16 + lr];
#pragma unroll
                for (int j = 0; j < 4; ++j) {
                    float v = acc[m][n][j] + bcol;
                    if (mode == 0) v = v > 0.f ? v + 1.f : __expf(v);
                    *(float*)(ep + (((lg * 4 + j) * 68) + n * 16 + lr) * 4) = v;
                }
            }
            asm volatile("s_waitcnt lgkmcnt(0)" ::: "memory");
            SCHED_FENCE();
            long R0b = row0 + wr * 128 + m * 16;
            if (mode == 0) {
                unsigned short* O = (unsigned short*)out;
#pragma unroll
                for (int i = 0; i < 2; ++i) {
                    int r = i * 8 + (lane >> 3), c8 = (lane & 7) * 8;
                    float4 u0 = *(const float4*)(ep + (r * 68 + c8) * 4);
                    float4 u1 = *(const float4*)(ep + (r * 68 + c8 + 4) * 4);
                    uint4 w;
                    w.x = pk2(u0.x, u0.y); w.y = pk2(u0.z, u0.w);
                    w.z = pk2(u1.x, u1.y); w.w = pk2(u1.z, u1.w);
                    *(uint4*)(O + (R0b + r) * 1024 + col0 + wc * 64 + c8) = w;
                }
            } else {
                float* O = (float*)out;
#pragma unroll
                for (int i = 0; i < 4; ++i) {
                    int r = i * 4 + (lane >> 4), c4 = (lane & 15) * 4;
                    float4 u = *(const float4*)(ep + (r * 68 + c4) * 4);
                    *(float4*)(O + (R0b + r) * 1024 + col0 + wc * 64 + c4) = u;
                }
            }
            asm volatile("s_waitcnt lgkmcnt(0)" ::: "memory");
            SCHED_FENCE();
        }
    } else {
        // transposed bf16 outputs (modes 1/2): 8B packed along s (j-contiguous)
#pragma unroll
        for (int m = 0; m < 8; ++m) {
#pragma unroll
            for (int n = 0; n < 4; ++n) {
                long col = col0 + wc * 64 + n * 16 + lr;
                float bcol = bias[col];
                long R0 = row0 + wr * 128 + m * 16 + r4;
                unsigned short* O = (unsigned short*)out;
                long nb = R0 >> 12;
                long s = R0 & 4095;
                short4v pack;
#pragma unroll
                for (int j = 0; j < 4; ++j) {
                    float v = acc[m][n][j] + bcol;
                    if (mode == 1) v = v > 0.f ? v + 1.f : __expf(v);
                    pack[j] = (short)f2bf(v);
                }
                *(short4v*)(O + ((nb << 10) + col) * 4096 + s) = pack;
            }
        }
    }
}

// ---- merged Q/K/V projection: 768 blocks, segment = blockIdx.x>>8 ----
__global__ __launch_bounds__(512, 1) void proj_gemm(const unsigned short* __restrict__ qb,
                                                    const unsigned short* __restrict__ kb,
                                                    const unsigned short* __restrict__ vb,
                                                    const unsigned short* __restrict__ Wqb,
                                                    const unsigned short* __restrict__ Wkb,
                                                    const unsigned short* __restrict__ Wvb,
                                                    const float* __restrict__ bq,
                                                    const float* __restrict__ bk,
                                                    const float* __restrict__ bv,
                                                    unsigned short* __restrict__ Qm,
                                                    unsigned short* __restrict__ Kt,
                                                    unsigned short* __restrict__ vT) {
    __shared__ __align__(16) char lds[131072];
    int seg = blockIdx.x >> 8;
    int bid = blockIdx.x & 255;
    const unsigned short* A = seg == 0 ? qb : seg == 1 ? kb : vb;
    const unsigned short* B = seg == 0 ? Wqb : seg == 1 ? Wkb : Wvb;
    const float* bias = seg == 0 ? bq : seg == 1 ? bk : bv;
    void* out = seg == 0 ? (void*)Qm : seg == 1 ? (void*)Kt : (void*)vT;
    gemm_body(A, B, bias, out, seg, lds, bid);   // mode 0/1/2 == seg
}

// ---- output projection: 256 blocks, mode 3 ----
__global__ __launch_bounds__(512, 1) void out_gemm(const unsigned short* __restrict__ Vbuf,
                                                   const unsigned short* __restrict__ Wob,
                                                   const float* __restrict__ bo,
                                                   float* __restrict__ out) {
    __shared__ __align__(16) char lds[131072];
    gemm_body(Vbuf, Wob, bo, out, 3, lds, blockIdx.x);
}

// ---------------- KV[n,h,m,d] = sum_s vT[...][s] * Kt[...][s]; Ksum fused from B-frags ----
__global__ __launch_bounds__(256) void kv_kernel(const unsigned short* __restrict__ Kt,
                                                 const unsigned short* __restrict__ vT,
                                                 float* __restrict__ KV,
                                                 float* __restrict__ Ksum) {
    int b = blockIdx.x;
    int sc = b & 7, h = (b >> 3) & 15, n = b >> 7;
    const int tid = threadIdx.x, lane = tid & 63, wave = tid >> 6;
    long base = ((long)(n * 1024 + h * 64)) * 4096 + sc * 512;
    const unsigned short* Kp = Kt + base;
    const unsigned short* Vp = vT + base;
    const int lr = lane & 15, lk = (lane >> 4) * 8;

    f32x4 acc[4] = {};
    float ksa[4] = {0.f, 0.f, 0.f, 0.f};
    for (int s0 = 0; s0 < 512; s0 += 32) {
        short8 a = *(const short8*)(Vp + (long)(wave * 16 + lr) * 4096 + s0 + lk);
#pragma unroll
        for (int d4 = 0; d4 < 4; ++d4) {
            short8 bb = *(const short8*)(Kp + (long)(d4 * 16 + lr) * 4096 + s0 + lk);
            acc[d4] = MFMA16(a, bb, acc[d4]);
            if (wave == 0) {
                float t = 0.f;
#pragma unroll
                for (int e = 0; e < 8; ++e) t += bf2f((unsigned short)bb[e]);
                ksa[d4] += t;
            }
        }
    }
    float* KVb = KV + (long)(n * 16 + h) * 4096;
#pragma unroll
    for (int d4 = 0; d4 < 4; ++d4)
#pragma unroll
        for (int j = 0; j < 4; ++j) {
            int m = wave * 16 + (lane >> 4) * 4 + j;
            int d = d4 * 16 + lr;
            atomicAdd(KVb + m * 64 + d, acc[d4][j]);
        }
    // Ksum: wave 0 holds per-(lr,lg) partials over (s0,lk); reduce over lg, one atomic per d
    if (wave == 0) {
#pragma unroll
        for (int d4 = 0; d4 < 4; ++d4) {
            float t = ksa[d4];
            t += __shfl_xor(t, 16, 64);
            t += __shfl_xor(t, 32, 64);
            if (lane < 16) atomicAdd(Ksum + n * 1024 + h * 64 + d4 * 16 + lane, t);
        }
    }
}

// ---------------- attn: V[n,l,h,m] = (sum_d Q[l,d]*KV[m,d]) / (Q[l,:]·Ksum + eps) ----------------
__global__ __launch_bounds__(256) void attn_kernel(const unsigned short* __restrict__ Qm,
                                                   const float* __restrict__ KV,
                                                   const float* __restrict__ Ksum,
                                                   unsigned short* __restrict__ Vbuf) {
    __shared__ unsigned short Qs[128 * 64];
    __shared__ unsigned short KVs[64 * 64];
    __shared__ float zin[128];
    __shared__ float ks[64];
    int b = blockIdx.x;
    int lc = b & 31, h = (b >> 5) & 15, n = b >> 9;
    int tid = threadIdx.x, lane = tid & 63, wave = tid >> 6;
    long l0 = (long)n * 4096 + lc * 128;

    const unsigned short* Qg = Qm + (l0 + (tid >> 3)) * 1024 + h * 64 + (tid & 7) * 8;
    char* QsB = (char*)Qs + (wave << 10);
#pragma unroll
    for (int it = 0; it < 4; ++it)
        async16(Qg + (long)it * 32 * 1024, QsB + it * 4096);

    const float* kvp = KV + (long)(n * 16 + h) * 4096;
    for (int i = tid * 4; i < 4096; i += 1024) {
        float4 v = *reinterpret_cast<const float4*>(kvp + i);
        short4v p;
        p[0] = (short)f2bf(v.x); p[1] = (short)f2bf(v.y);
        p[2] = (short)f2bf(v.z); p[3] = (short)f2bf(v.w);
        *(short4v*)(KVs + i) = p;
    }
    if (tid < 64) ks[tid] = Ksum[n * 1024 + h * 64 + tid];
    __syncthreads();

    // wave-parallel normalizer: 2 threads per row, 32 d each, shfl_xor combine
    {
        int row = tid >> 1, half = tid & 1;
        float den = 0.f;
        const unsigned short* qrow = Qs + row * 64 + half * 32;
#pragma unroll
        for (int d = 0; d < 32; ++d) den += bf2f(qrow[d]) * ks[half * 32 + d];
        den += __shfl_xor(den, 1, 64);
        if (half == 0) zin[row] = 1.0f / (den + 1e-6f);
    }
    __syncthreads();

    const int lr = lane & 15, lk = (lane >> 4) * 8;
    f32x4 acc[2][4] = {};
#pragma unroll
    for (int kk = 0; kk < 2; ++kk) {
        short8 a0 = *(const short8*)(Qs + (wave * 32 + lr) * 64 + kk * 32 + lk);
        short8 a1 = *(const short8*)(Qs + (wave * 32 + 16 + lr) * 64 + kk * 32 + lk);
#pragma unroll
        for (int nn = 0; nn < 4; ++nn) {
            short8 bb = *(const short8*)(KVs + (nn * 16 + lr) * 64 + kk * 32 + lk);
            acc[0][nn] = MFMA16(a0, bb, acc[0][nn]);
            acc[1][nn] = MFMA16(a1, bb, acc[1][nn]);
        }
    }

    // ---- coalesced epilogue: stage [16 rows][64 cols] f32 into this wave's own dead
    // Qs rows (wave*4096..+4096 bytes), then 16B stores. Wave-private region: no barrier.
    {
        char* ep = (char*)Qs + wave * 4096;
#pragma unroll
        for (int mi = 0; mi < 2; ++mi) {
#pragma unroll
            for (int nn = 0; nn < 4; ++nn)
#pragma unroll
                for (int j = 0; j < 4; ++j) {
                    int rloc = (lane >> 4) * 4 + j;
                    float v = acc[mi][nn][j] * zin[wave * 32 + mi * 16 + rloc];
                    *(float*)(ep + (rloc * 64 + nn * 16 + lr) * 4) = v;
                }
            asm volatile("s_waitcnt lgkmcnt(0)" ::: "memory");
            SCHED_FENCE();
#pragma unroll
            for (int i = 0; i < 2; ++i) {
                int r = i * 8 + (lane >> 3), c8 = (lane & 7) * 8;
                float4 u0 = *(const float4*)(ep + (r * 64 + c8) * 4);
                float4 u1 = *(const float4*)(ep + (r * 64 + c8 + 4) * 4);
                uint4 w;
                w.x = pk2(u0.x, u0.y); w.y = pk2(u0.z, u0.w);
                w.z = pk2(u1.x, u1.y); w.w = pk2(u1.z, u1.w);
                *(uint4*)(Vbuf + (l0 + wave * 32 + mi * 16 + r) * 1024 + h * 64 + c8) = w;
            }
            asm volatile("s_waitcnt lgkmcnt(0)" ::: "memory");
            SCHED_FENCE();
        }
    }
}

extern "C" void kernel_launch(void* const* d_in, const int* in_sizes, int n_in,
                              void* d_out, int out_size, void* d_ws, size_t ws_size,
                              hipStream_t stream) {
    const float* queries = (const float*)d_in[0];
    const float* keys    = (const float*)d_in[1];
    const float* values  = (const float*)d_in[2];
    const float* Wq = (const float*)d_in[3];
    const float* bq = (const float*)d_in[4];
    const float* Wk = (const float*)d_in[5];
    const float* bk = (const float*)d_in[6];
    const float* Wv = (const float*)d_in[7];
    const float* bv = (const float*)d_in[8];
    const float* Wo = (const float*)d_in[9];
    const float* bo = (const float*)d_in[10];
    float* out = (float*)d_out;

    char* ws = (char*)d_ws;
    const size_t SZ = (size_t)16384 * 1024 * 2;  // 33.5 MB bf16 matrix
    const size_t WSZ = (size_t)1024 * 1024 * 2;  // 2 MB bf16 weight
    unsigned short* qb  = (unsigned short*)(ws);
    unsigned short* kb  = (unsigned short*)(ws + SZ);
    unsigned short* vb  = (unsigned short*)(ws + 2 * SZ);
    unsigned short* Wqb = (unsigned short*)(ws + 3 * SZ);
    unsigned short* Wkb = (unsigned short*)(ws + 3 * SZ + WSZ);
    unsigned short* Wvb = (unsigned short*)(ws + 3 * SZ + 2 * WSZ);
    unsigned short* Wob = (unsigned short*)(ws + 3 * SZ + 3 * WSZ);
    unsigned short* Qm  = (unsigned short*)(ws + 3 * SZ + 4 * WSZ);
    unsigned short* Kt  = (unsigned short*)(ws + 4 * SZ + 4 * WSZ);
    unsigned short* vT  = (unsigned short*)(ws + 5 * SZ + 4 * WSZ);
    float* KVf = (float*)(ws + 6 * SZ + 4 * WSZ);
    float* Ksf = (float*)(ws + 6 * SZ + 4 * WSZ + 1048576);
    unsigned short* Vbuf = qb;  // alias: qb dead after projections

    cvt_all<<<6656, 256, 0, stream>>>(queries, keys, values, Wq, Wk, Wv, Wo,
                                      qb, kb, vb, Wqb, Wkb, Wvb, Wob);

    proj_gemm<<<768, 512, 0, stream>>>(qb, kb, vb, Wqb, Wkb, Wvb, bq, bk, bv, Qm, Kt, vT);

    hipMemsetAsync(KVf, 0, 1048576 + 16384, stream);
    kv_kernel<<<512, 256, 0, stream>>>(Kt, vT, KVf, Ksf);
    attn_kernel<<<2048, 256, 0, stream>>>(Qm, KVf, Ksf, Vbuf);

    out_gemm<<<256, 512, 0, stream>>>(Vbuf, Wob, bo, out);
}